// Round 1
// baseline (3565.557 us; speedup 1.0000x reference)
//
#include <hip/hip_runtime.h>
#include <hip/hip_cooperative_groups.h>

namespace cg = cooperative_groups;

// ---------------------------------------------------------------------------
// SparsePoolingLayer: u0 = conv5x5_valid(x, W_ff); iterate
//   u <- 0.5*u + 0.5*(u0 - W_rec @ a); a = relu(u - thr)
// until ||u_new - u||/||u_new|| < 1e-3 (device-checked), max 41 iterations.
//
// R9 design: persistent cooperative iteration kernel.
//  - grid 450 x 256 threads, 4 tiles of 64 n per block; u state lives in
//    128 VGPRs (4 x 8 x int4 packed fp16), statically indexed.
//  - per-iteration HBM traffic: 59 MB (u0 read only) vs 177 MB before
//    (u read + u0 read + u write). u written once after convergence.
//  - one grid.sync() per iteration; convergence from device-scope atomic
//    loads of the block-reduced norms (same 1e-6*n2 semantics, max 41 bodies).
//  - u0 stored fp16 (was bf16): free accuracy (~8x less u0 rounding error).
//  - fallback: if hipLaunchCooperativeKernel errors, the old 41-launch
//    path (iter_kernel<FIRST>) runs instead.
// ---------------------------------------------------------------------------

typedef __attribute__((ext_vector_type(8))) short short8;
typedef __attribute__((ext_vector_type(4))) float f32x4;

#define NTOT 115200   // 32*60*60
#define CHW  262144   // 64*64*64
#define HW2  4096     // 64*64
#define LDA  264      // a_lds row stride in shorts (528 B)

__device__ __forceinline__ unsigned short f2bf(float f) {
  unsigned int u = __float_as_uint(f);
  unsigned int r = u + 0x7FFFu + ((u >> 16) & 1u);
  return (unsigned short)(r >> 16);
}
__device__ __forceinline__ float bf2f(unsigned short h) {
  return __uint_as_float(((unsigned int)h) << 16);
}
__device__ __forceinline__ unsigned short f2h(float f) {
  _Float16 x = (_Float16)f;
  unsigned short r;
  __builtin_memcpy(&r, &x, 2);
  return r;
}
__device__ __forceinline__ float h2f(unsigned short h) {
  _Float16 x;
  __builtin_memcpy(&x, &h, 2);
  return (float)x;
}

// ---------------------------------------------------------------------------
// Weight prep:
//  wff[o][(ky*5+kx)*64+ci] bf16  (conv A operand rows)
//  wrec_sw: per-lane MFMA fragment order: for 8-wide ic-chunk cc (0..31),
//  oc row o: wrec_sw[((cc*256)+o)*8 + j] = W_rec[o][cc*8+j]
__global__ void cast_weights(const float* __restrict__ wff_f,
                             const float* __restrict__ wrec_f,
                             unsigned short* __restrict__ wff,
                             unsigned short* __restrict__ wrec_sw) {
  int tid = blockIdx.x * 256 + threadIdx.x;
  if (tid < 409600) {
    int o = tid / 1600, k = tid % 1600;
    int kk = k >> 6, ci = k & 63;            // k = kk*64 + ci
    wff[tid] = f2bf(wff_f[o * 1600 + ci * 25 + kk]);
  } else if (tid < 409600 + 65536) {
    int i = tid - 409600;
    int o = i >> 8, ic = i & 255;
    wrec_sw[(((ic >> 3) << 8) + o) * 8 + (ic & 7)] = f2bf(wrec_f[i]);
  }
}

// ---------------------------------------------------------------------------
// x NCHW fp32 -> NHWC bf16: xt[(b*4096 + y*64 + x)*64 + ci].
__global__ __launch_bounds__(256) void transpose_x(
    const float* __restrict__ x, unsigned short* __restrict__ xt) {
  int g = blockIdx.x * 256 + threadIdx.x;          // 131072 = 32*4096
  const float* src = x + (long)(g >> 12) * CHW + (g & 4095);
  unsigned short* dst = xt + (long)g * 64;
#pragma unroll
  for (int oct = 0; oct < 8; ++oct) {
    alignas(16) unsigned short tmp[8];
#pragma unroll
    for (int d = 0; d < 8; ++d)
      tmp[d] = f2bf(src[(oct * 8 + d) * HW2]);
    *(int4*)(dst + oct * 8) = *(const int4*)tmp;
  }
}

// ---------------------------------------------------------------------------
// Conv as implicit GEMM, D[oc][n] (A = wff, B = x). Block 128oc x 128n,
// BK=32, grid (900, 2). Writes u0 fp16 [n][oc] as uint2 (4 oc per lane).
__global__ __launch_bounds__(256) void conv_kernel(
    const unsigned short* __restrict__ xt,
    const unsigned short* __restrict__ wff,
    unsigned short* __restrict__ u0_nc) {
  __shared__ short As[128 * 40];   // x-tile  [n][k]  pad 32->40
  __shared__ short Bs[128 * 40];   // wff     [oc][k]
  const int t = threadIdx.x;
  const int n0 = blockIdx.x * 128;
  const int oc0 = blockIdx.y * 128;
  const int lane = t & 63, w = t >> 6;
  const int q = lane >> 4, r = lane & 15;
  const int woc = w >> 1, wn = w & 1;      // oc-half, n-half
  const int qt = t & 3, mrow = t >> 2;     // staging: row mrow(+64), 16B qt

  int xbase[2];
#pragma unroll
  for (int p = 0; p < 2; ++p) {
    int n = n0 + p * 64 + mrow;
    int bb = n / 3600, rem = n - bb * 3600;
    int yy = rem / 60, xx = rem - yy * 60;
    xbase[p] = (bb * 4096 + yy * 64 + xx) * 64 + qt * 8;
  }

  f32x4 acc[4][4];
#pragma unroll
  for (int i = 0; i < 4; i++)
#pragma unroll
    for (int j = 0; j < 4; j++) acc[i][j] = (f32x4){0.f, 0.f, 0.f, 0.f};

  for (int c = 0; c < 50; ++c) {
    const int k0 = c * 32;
    const int kk = c >> 1;                 // ky*5+kx, uniform per chunk
    const int ky = kk / 5, kx = kk - ky * 5;
    const int choff = (ky * 64 + kx) * 64 + (c & 1) * 32;  // scalar-uniform

    __syncthreads();
#pragma unroll
    for (int p = 0; p < 2; ++p) {          // wff: 128 oc-rows x 32 k
      int m = p * 64 + mrow;
      *(int4*)(&Bs[m * 40 + qt * 8]) =
          *(const int4*)(wff + (oc0 + m) * 1600 + k0 + qt * 8);
    }
#pragma unroll
    for (int p = 0; p < 2; ++p) {          // x-tile: contiguous bf16 (NHWC)
      int m = p * 64 + mrow;
      *(int4*)(&As[m * 40 + qt * 8]) = *(const int4*)(xt + xbase[p] + choff);
    }
    __syncthreads();

    short8 xf[4], wf[4];
#pragma unroll
    for (int j = 0; j < 4; j++)
      xf[j] = *(const short8*)(&As[(wn * 64 + j * 16 + r) * 40 + q * 8]);
#pragma unroll
    for (int i = 0; i < 4; i++)
      wf[i] = *(const short8*)(&Bs[(woc * 64 + i * 16 + r) * 40 + q * 8]);
#pragma unroll
    for (int i = 0; i < 4; i++)
#pragma unroll
      for (int j = 0; j < 4; j++)
        acc[i][j] = __builtin_amdgcn_mfma_f32_16x16x32_bf16(wf[i], xf[j],
                                                            acc[i][j], 0, 0, 0);
  }

  // epilogue: lane holds 4 consecutive oc (d) at fixed n -> uint2 stores
#pragma unroll
  for (int j = 0; j < 4; j++) {
    const int n = n0 + wn * 64 + j * 16 + r;
#pragma unroll
    for (int i = 0; i < 4; i++) {
      const int oc = oc0 + woc * 64 + i * 16 + q * 4;
      alignas(8) unsigned short up[4];
#pragma unroll
      for (int d = 0; d < 4; ++d) up[d] = f2h(acc[i][j][d]);   // fp16 u0
      *(uint2*)(&u0_nc[n * 256 + oc]) = *(const uint2*)up;
    }
  }
}

// ---------------------------------------------------------------------------
// R9: persistent cooperative iteration kernel.
// grid 450 x 256 threads; block owns n in [450*bid, +256) = 4 tiles x 64 n.
// Per tile: P1 build a (bf16) into LDS from reg-state u; P2 GEMM rec =
// W_rec @ a (M=256 oc, N=64 n, K=256); P3 rec -> LDS fp16; P4 u-update in
// regs + norm accumulation. After all tiles: block-reduce, atomicAdd norms,
// grid.sync, uniform convergence decision. u written to HBM once at end.
__global__ __launch_bounds__(256, 2) void iter_persist(
    const unsigned short* __restrict__ wrec_sw,
    const unsigned short* __restrict__ u0,
    const float* __restrict__ thr,
    unsigned short* __restrict__ u,
    float* __restrict__ norms) {
  __shared__ short a_lds[64 * LDA];
  __shared__ float red[8];

  const int t = threadIdx.x;
  const int ch = t & 31;                   // 8-oc chunk
  const int row0 = t >> 5;                 // rows row0 + 8p within tile
  const int occh = ch * 8;
  const int lane = t & 63, w = t >> 6;
  const int q = lane >> 4, r = lane & 15;
  const int nblk = blockIdx.x * 256;

  float4 th0 = *(const float4*)(thr + occh);
  float4 th1 = *(const float4*)(thr + occh + 4);
  float thc[8] = {th0.x, th0.y, th0.z, th0.w, th1.x, th1.y, th1.z, th1.w};

  int4 sv[4][8];                           // u state, packed fp16: 128 VGPRs

  cg::grid_group grid = cg::this_grid();
  int done = 0;

  // ---- iteration 1 (peeled: u_old = 0, a from u0, stash u0 in sv) ----
  {
    float d2 = 0.f, n2 = 0.f;
#pragma unroll
    for (int tile = 0; tile < 4; ++tile) {
      const int tb = (nblk + tile * 64 + row0) * 256 + occh;
      // P1: a0 = relu(u0 - thr); sv <- u0 (fp16, identity copy)
#pragma unroll
      for (int p = 0; p < 8; ++p) {
        int4 raw = *(const int4*)(u0 + tb + p * 2048);   // 8 fp16
        sv[tile][p] = raw;
        const unsigned short* hs = (const unsigned short*)&raw;
        alignas(16) unsigned short ap[8];
#pragma unroll
        for (int d = 0; d < 8; ++d) {
          float a = h2f(hs[d]) - thc[d];
          ap[d] = f2bf(a > 0.f ? a : 0.f);
        }
        *(int4*)(&a_lds[(row0 + p * 8) * LDA + occh]) = *(const int4*)ap;
      }
      __syncthreads();

      // P2: GEMM
      f32x4 acc[4][4];
#pragma unroll
      for (int i = 0; i < 4; i++)
#pragma unroll
        for (int j = 0; j < 4; j++) acc[i][j] = (f32x4){0.f, 0.f, 0.f, 0.f};
#pragma unroll
      for (int c = 0; c < 8; ++c) {
        short8 afr[4], bfr[4];
#pragma unroll
        for (int i = 0; i < 4; i++)
          afr[i] = *(const short8*)(wrec_sw +
                   (((c * 4 + q) << 8) + w * 64 + i * 16 + r) * 8);
#pragma unroll
        for (int j = 0; j < 4; j++)
          bfr[j] = *(const short8*)(&a_lds[(j * 16 + r) * LDA + c * 32 + q * 8]);
#pragma unroll
        for (int i = 0; i < 4; i++)
#pragma unroll
          for (int j = 0; j < 4; j++)
            acc[i][j] = __builtin_amdgcn_mfma_f32_16x16x32_bf16(
                afr[i], bfr[j], acc[i][j], 0, 0, 0);
      }
      __syncthreads();

      // P3: rec -> a_lds fp16
#pragma unroll
      for (int j = 0; j < 4; j++) {
        const int nr = j * 16 + r;
#pragma unroll
        for (int i = 0; i < 4; i++) {
          const int oc = w * 64 + i * 16 + q * 4;
          alignas(8) unsigned short rp[4];
#pragma unroll
          for (int d = 0; d < 4; ++d) rp[d] = f2h(acc[i][j][d]);
          *(uint2*)(&a_lds[nr * LDA + oc]) = *(const uint2*)rp;
        }
      }
      __syncthreads();

      // P4: u1 = 0.5*(u0 - rec); d2 = n2 = sum u1^2
#pragma unroll
      for (int p = 0; p < 8; ++p) {
        int4 rr = *(const int4*)(&a_lds[(row0 + p * 8) * LDA + occh]);
        const unsigned short* rs = (const unsigned short*)&rr;
        const unsigned short* hs = (const unsigned short*)&sv[tile][p];
        alignas(16) unsigned short up[8];
#pragma unroll
        for (int d = 0; d < 8; ++d) {
          float un = 0.5f * (h2f(hs[d]) - h2f(rs[d]));
          d2 += un * un;
          n2 += un * un;
          up[d] = f2h(un);
        }
        sv[tile][p] = *(const int4*)up;
      }
      __syncthreads();                     // a_lds reused by next tile
    }

#pragma unroll
    for (int off = 32; off; off >>= 1) {
      d2 += __shfl_down(d2, off, 64);
      n2 += __shfl_down(n2, off, 64);
    }
    if (lane == 0) { red[w] = d2; red[4 + w] = n2; }
    __syncthreads();
    if (t == 0) {
      atomicAdd(&norms[2], red[0] + red[1] + red[2] + red[3]);
      atomicAdd(&norms[3], red[4] + red[5] + red[6] + red[7]);
    }
    grid.sync();
    float d2g = __hip_atomic_load(&norms[2], __ATOMIC_RELAXED,
                                  __HIP_MEMORY_SCOPE_AGENT);
    float n2g = __hip_atomic_load(&norms[3], __ATOMIC_RELAXED,
                                  __HIP_MEMORY_SCOPE_AGENT);
    done = (d2g < 1e-6f * n2g) ? 1 : 0;
  }

  // ---- iterations 2..41 ----
  for (int it = 2; it <= 41 && !done; ++it) {
    float d2 = 0.f, n2 = 0.f;
#pragma unroll
    for (int tile = 0; tile < 4; ++tile) {
      const int tb = (nblk + tile * 64 + row0) * 256 + occh;
      // P1: a = relu(u - thr) from regs (no global traffic)
#pragma unroll
      for (int p = 0; p < 8; ++p) {
        const unsigned short* hs = (const unsigned short*)&sv[tile][p];
        alignas(16) unsigned short ap[8];
#pragma unroll
        for (int d = 0; d < 8; ++d) {
          float a = h2f(hs[d]) - thc[d];
          ap[d] = f2bf(a > 0.f ? a : 0.f);
        }
        *(int4*)(&a_lds[(row0 + p * 8) * LDA + occh]) = *(const int4*)ap;
      }
      __syncthreads();

      // P2: GEMM
      f32x4 acc[4][4];
#pragma unroll
      for (int i = 0; i < 4; i++)
#pragma unroll
        for (int j = 0; j < 4; j++) acc[i][j] = (f32x4){0.f, 0.f, 0.f, 0.f};
#pragma unroll
      for (int c = 0; c < 8; ++c) {
        short8 afr[4], bfr[4];
#pragma unroll
        for (int i = 0; i < 4; i++)
          afr[i] = *(const short8*)(wrec_sw +
                   (((c * 4 + q) << 8) + w * 64 + i * 16 + r) * 8);
#pragma unroll
        for (int j = 0; j < 4; j++)
          bfr[j] = *(const short8*)(&a_lds[(j * 16 + r) * LDA + c * 32 + q * 8]);
#pragma unroll
        for (int i = 0; i < 4; i++)
#pragma unroll
          for (int j = 0; j < 4; j++)
            acc[i][j] = __builtin_amdgcn_mfma_f32_16x16x32_bf16(
                afr[i], bfr[j], acc[i][j], 0, 0, 0);
      }
      __syncthreads();

      // P3: rec -> a_lds fp16
#pragma unroll
      for (int j = 0; j < 4; j++) {
        const int nr = j * 16 + r;
#pragma unroll
        for (int i = 0; i < 4; i++) {
          const int oc = w * 64 + i * 16 + q * 4;
          alignas(8) unsigned short rp[4];
#pragma unroll
          for (int d = 0; d < 4; ++d) rp[d] = f2h(acc[i][j][d]);
          *(uint2*)(&a_lds[nr * LDA + oc]) = *(const uint2*)rp;
        }
      }
      __syncthreads();

      // P4: u_new = 0.5*u + 0.5*(u0 - rec); norms; update regs
#pragma unroll
      for (int p = 0; p < 8; ++p) {
        int4 rr = *(const int4*)(&a_lds[(row0 + p * 8) * LDA + occh]);
        int4 u0p = *(const int4*)(u0 + tb + p * 2048);   // only HBM read
        const unsigned short* rs = (const unsigned short*)&rr;
        const unsigned short* us = (const unsigned short*)&u0p;
        const unsigned short* hs = (const unsigned short*)&sv[tile][p];
        alignas(16) unsigned short up[8];
#pragma unroll
        for (int d = 0; d < 8; ++d) {
          float uo = h2f(hs[d]);
          float un = 0.5f * uo + 0.5f * (h2f(us[d]) - h2f(rs[d]));
          float df = un - uo;
          d2 += df * df;
          n2 += un * un;
          up[d] = f2h(un);
        }
        sv[tile][p] = *(const int4*)up;
      }
      __syncthreads();
    }

#pragma unroll
    for (int off = 32; off; off >>= 1) {
      d2 += __shfl_down(d2, off, 64);
      n2 += __shfl_down(n2, off, 64);
    }
    if (lane == 0) { red[w] = d2; red[4 + w] = n2; }
    __syncthreads();
    if (t == 0) {
      atomicAdd(&norms[2 * it], red[0] + red[1] + red[2] + red[3]);
      atomicAdd(&norms[2 * it + 1], red[4] + red[5] + red[6] + red[7]);
    }
    grid.sync();
    float d2g = __hip_atomic_load(&norms[2 * it], __ATOMIC_RELAXED,
                                  __HIP_MEMORY_SCOPE_AGENT);
    float n2g = __hip_atomic_load(&norms[2 * it + 1], __ATOMIC_RELAXED,
                                  __HIP_MEMORY_SCOPE_AGENT);
    done = (d2g < 1e-6f * n2g) ? 1 : 0;
  }

  // ---- write final u (once) ----
#pragma unroll
  for (int tile = 0; tile < 4; ++tile)
#pragma unroll
    for (int p = 0; p < 8; ++p)
      *(int4*)(u + (nblk + tile * 64 + row0 + p * 8) * 256 + occh) =
          sv[tile][p];
}

// ---------------------------------------------------------------------------
// Fallback path (used only if cooperative launch is unavailable).
// Same as R8 iter_kernel but u0 is now fp16.
template <int FIRST>
__global__ __launch_bounds__(256, 3) void iter_kernel(
    const unsigned short* __restrict__ wrec_sw,
    const unsigned short* __restrict__ u0, const float* __restrict__ thr,
    unsigned short* __restrict__ u, float* __restrict__ norms,
    int* __restrict__ flag, int it) {
  __shared__ short a_lds[64 * LDA];
  __shared__ float red[8];

  const int t = threadIdx.x;
  if (!FIRST) {
    if (*(volatile int*)flag) return;                      // converged earlier
    float d2p = norms[2 * (it - 1)], n2p = norms[2 * (it - 1) + 1];
    if (d2p < 1e-6f * n2p) {                               // fro ratio < 1e-3
      if (t == 0) *flag = 1;
      return;
    }
  }

  const int n0 = blockIdx.x * 64;
  const int ch = t & 31;                   // 8-oc chunk
  const int row0 = t >> 5;                 // rows row0 + 8p
  const int occh = ch * 8;

  float4 th0 = *(const float4*)(thr + occh);
  float4 th1 = *(const float4*)(thr + occh + 4);
  float thc[8] = {th0.x, th0.y, th0.z, th0.w, th1.x, th1.y, th1.z, th1.w};

  // ---- phase 1: stage; sv = packed fp16 of staged value ----
  int4 sv[8];
#pragma unroll
  for (int p = 0; p < 8; ++p) {
    const int base = (n0 + row0 + p * 8) * 256 + occh;
    alignas(16) unsigned short ap[8];
    if (FIRST) {
      int4 raw = *(const int4*)(u0 + base);        // 8 fp16
      sv[p] = raw;
      const unsigned short* hs = (const unsigned short*)&raw;
#pragma unroll
      for (int d = 0; d < 8; ++d) {
        float a = h2f(hs[d]) - thc[d];
        ap[d] = f2bf(a > 0.f ? a : 0.f);
      }
    } else {
      sv[p] = *(const int4*)(u + base);            // 8 fp16
      const unsigned short* hs = (const unsigned short*)&sv[p];
#pragma unroll
      for (int d = 0; d < 8; ++d) {
        float a = h2f(hs[d]) - thc[d];
        ap[d] = f2bf(a > 0.f ? a : 0.f);
      }
    }
    *(int4*)(&a_lds[(row0 + p * 8) * LDA + occh]) = *(const int4*)ap;
  }
  __syncthreads();

  // ---- phase 2: GEMM ----
  const int lane = t & 63, w = t >> 6;
  const int q = lane >> 4, r = lane & 15;

  f32x4 acc[4][4];
#pragma unroll
  for (int i = 0; i < 4; i++)
#pragma unroll
    for (int j = 0; j < 4; j++) acc[i][j] = (f32x4){0.f, 0.f, 0.f, 0.f};

#pragma unroll
  for (int c = 0; c < 8; ++c) {
    short8 afr[4], bfr[4];
#pragma unroll
    for (int i = 0; i < 4; i++)
      afr[i] = *(const short8*)(wrec_sw +
               (((c * 4 + q) << 8) + w * 64 + i * 16 + r) * 8);
#pragma unroll
    for (int j = 0; j < 4; j++)
      bfr[j] = *(const short8*)(&a_lds[(j * 16 + r) * LDA + c * 32 + q * 8]);
#pragma unroll
    for (int i = 0; i < 4; i++)
#pragma unroll
      for (int j = 0; j < 4; j++)
        acc[i][j] = __builtin_amdgcn_mfma_f32_16x16x32_bf16(afr[i], bfr[j],
                                                            acc[i][j], 0, 0, 0);
  }

  // ---- phase 3: rec (C-layout) -> a_lds row-major, fp16 ----
  __syncthreads();                         // all a_lds GEMM reads done
#pragma unroll
  for (int j = 0; j < 4; j++) {
    const int nr = j * 16 + r;
#pragma unroll
    for (int i = 0; i < 4; i++) {
      const int oc = w * 64 + i * 16 + q * 4;
      alignas(8) unsigned short rp[4];
#pragma unroll
      for (int d = 0; d < 4; ++d) rp[d] = f2h(acc[i][j][d]);
      *(uint2*)(&a_lds[nr * LDA + oc]) = *(const uint2*)rp;
    }
  }
  __syncthreads();

  // ---- phase 4: coalesced u update + norms ----
  float d2 = 0.f, n2 = 0.f;
#pragma unroll
  for (int p = 0; p < 8; ++p) {
    const int base = (n0 + row0 + p * 8) * 256 + occh;
    int4 rr = *(const int4*)(&a_lds[(row0 + p * 8) * LDA + occh]);  // rec fp16
    const unsigned short* rs = (const unsigned short*)&rr;
    const unsigned short* hs = (const unsigned short*)&sv[p];
    float u0v[8];
    if (FIRST) {
#pragma unroll
      for (int d = 0; d < 8; ++d) u0v[d] = h2f(hs[d]);
    } else {
      int4 u0p = *(const int4*)(u0 + base);
      const unsigned short* us = (const unsigned short*)&u0p;
#pragma unroll
      for (int d = 0; d < 8; ++d) u0v[d] = h2f(us[d]);
    }
    alignas(16) unsigned short up[8];
#pragma unroll
    for (int d = 0; d < 8; ++d) {
      float uo = FIRST ? 0.f : h2f(hs[d]);
      float un = 0.5f * uo + 0.5f * (u0v[d] - h2f(rs[d]));
      float df = un - uo;
      d2 += df * df;
      n2 += un * un;
      up[d] = f2h(un);
    }
    *(int4*)(u + base) = *(const int4*)up;
  }

#pragma unroll
  for (int off = 32; off; off >>= 1) {
    d2 += __shfl_down(d2, off, 64);
    n2 += __shfl_down(n2, off, 64);
  }
  if (lane == 0) { red[w] = d2; red[4 + w] = n2; }
  __syncthreads();
  if (t == 0) {
    atomicAdd(&norms[2 * it], red[0] + red[1] + red[2] + red[3]);
    atomicAdd(&norms[2 * it + 1], red[4] + red[5] + red[6] + red[7]);
  }
}

// ---------------------------------------------------------------------------
// Final: out(NCHW fp32) = relu(u - thr), u fp16 [n][oc]. Block = 64 n; wave
// w handles oc [64w, 64w+64) = 8 int4 groups of 8 fp16.
__global__ __launch_bounds__(256) void final_out(
    const unsigned short* __restrict__ u, const float* __restrict__ thr,
    float* __restrict__ out) {
  const int t = threadIdx.x, lane = t & 63, w = t >> 6;
  const int n = blockIdx.x * 64 + lane;
  const int b = n / 3600, s = n - b * 3600;
  float* ob = out + (long)b * 921600 + s;
  const unsigned short* ub = u + (long)n * 256 + w * 64;
#pragma unroll
  for (int g = 0; g < 8; ++g) {            // 8 groups x 8 fp16 = 64 oc
    int4 raw = *(const int4*)(ub + g * 8);
    const unsigned short* rs = (const unsigned short*)&raw;
#pragma unroll
    for (int d = 0; d < 8; ++d) {
      int oc = w * 64 + g * 8 + d;
      float v = h2f(rs[d]) - thr[oc];
      ob[oc * 3600] = v > 0.f ? v : 0.f;
    }
  }
}

// ---------------------------------------------------------------------------
extern "C" void kernel_launch(void* const* d_in, const int* in_sizes, int n_in,
                              void* d_out, int out_size, void* d_ws,
                              size_t ws_size, hipStream_t stream) {
  const float* x      = (const float*)d_in[0];
  const float* wff_f  = (const float*)d_in[1];
  const float* wrec_f = (const float*)d_in[2];
  const float* thr    = (const float*)d_in[3];
  float* out = (float*)d_out;

  char* ws = (char*)d_ws;
  int* flag = (int*)ws;                                      // [0,4)
  float* norms = (float*)(ws + 64);                          // [64, 400)
  unsigned short* wff     = (unsigned short*)(ws + 1024);      // 819200 B
  unsigned short* wrec_sw = (unsigned short*)(ws + 851968);    // 131072 B
  // xt (16.8 MB) aliases the head of u (59 MB): xt dies after conv, u is
  // first written by iter_persist's final store (or fallback iter_kernel<1>).
  unsigned short* xt = (unsigned short*)(ws + 983040);
  unsigned short* u  = (unsigned short*)(ws + 983040);         // 58982400 B
  unsigned short* u0 = (unsigned short*)(ws + 59965440);       // 58982400 B
  // total ws: ~119 MB

  hipMemsetAsync(d_ws, 0, 1024, stream);  // flag + norm slots
  cast_weights<<<1856, 256, 0, stream>>>(wff_f, wrec_f, wff, wrec_sw);
  transpose_x<<<512, 256, 0, stream>>>(x, xt);
  conv_kernel<<<dim3(900, 2), 256, 0, stream>>>(xt, wff, u0);

  // primary path: persistent cooperative iteration (1 launch)
  const unsigned short* p_wrec = wrec_sw;
  const unsigned short* p_u0 = u0;
  const float* p_thr = thr;
  unsigned short* p_u = u;
  float* p_norms = norms;
  void* cargs[] = {(void*)&p_wrec, (void*)&p_u0, (void*)&p_thr, (void*)&p_u,
                   (void*)&p_norms};
  hipError_t rc = hipLaunchCooperativeKernel(
      (const void*)iter_persist, dim3(450), dim3(256), cargs, 0, stream);
  if (rc != hipSuccess) {
    // fallback: 41-launch loop with early-exit stubs
    iter_kernel<1><<<1800, 256, 0, stream>>>(wrec_sw, u0, thr, u, norms, flag,
                                             1);
    for (int it = 2; it <= 41; ++it)
      iter_kernel<0><<<1800, 256, 0, stream>>>(wrec_sw, u0, thr, u, norms,
                                               flag, it);
  }

  final_out<<<1800, 256, 0, stream>>>(u, thr, out);
}

// Round 2
// 1418.566 us; speedup vs baseline: 2.5135x; 2.5135x over previous
//
#include <hip/hip_runtime.h>

// ---------------------------------------------------------------------------
// SparsePoolingLayer: u0 = conv5x5_valid(x, W_ff); iterate
//   u <- 0.5*u + 0.5*(u0 - W_rec @ a); a = relu(u - thr)
// until ||u_new - u||/||u_new|| < 1e-3 (device-checked), max 41 iterations.
//
// R10 design: paired-iteration launches (2 fixed-point steps per kernel).
//  - R9 post-mortem: cooperative+register-resident u spilled to scratch
//    (WRITE_SIZE 1.56 GB vs 60 MB expected) at 8 waves/CU -> 2x SLOWER.
//  - R10: non-cooperative, 1800 blocks, 2 iterations per launch. u0 is read
//    once into 32 packed-fp16 VGPRs and reused by both steps; the odd-step
//    state u_A stays in registers between steps. Traffic/iter: 118 MB
//    (was 177), launches halved.
//  - Exact reference iteration count: each pair writes BOTH u_A (odd) and
//    u_B (even); sel_kernel scans norms for the first it with
//    d2 < 1e-6*n2 and final_out reads the matching buffer. fp16 chain
//    numerics identical to the single-step path.
//  - Fallback if ws_size can't hold the third u buffer: proven single-step
//    multi-launch path.
// ---------------------------------------------------------------------------

typedef __attribute__((ext_vector_type(8))) short short8;
typedef __attribute__((ext_vector_type(4))) float f32x4;

#define NTOT 115200   // 32*60*60
#define CHW  262144   // 64*64*64
#define HW2  4096     // 64*64
#define LDA  264      // a_lds row stride in shorts (528 B)

__device__ __forceinline__ unsigned short f2bf(float f) {
  unsigned int u = __float_as_uint(f);
  unsigned int r = u + 0x7FFFu + ((u >> 16) & 1u);
  return (unsigned short)(r >> 16);
}
__device__ __forceinline__ float bf2f(unsigned short h) {
  return __uint_as_float(((unsigned int)h) << 16);
}
__device__ __forceinline__ unsigned short f2h(float f) {
  _Float16 x = (_Float16)f;
  unsigned short r;
  __builtin_memcpy(&r, &x, 2);
  return r;
}
__device__ __forceinline__ float h2f(unsigned short h) {
  _Float16 x;
  __builtin_memcpy(&x, &h, 2);
  return (float)x;
}

// ---------------------------------------------------------------------------
// Weight prep:
//  wff[o][(ky*5+kx)*64+ci] bf16  (conv A operand rows)
//  wrec_sw: per-lane MFMA fragment order: for 8-wide ic-chunk cc (0..31),
//  oc row o: wrec_sw[((cc*256)+o)*8 + j] = W_rec[o][cc*8+j]
__global__ void cast_weights(const float* __restrict__ wff_f,
                             const float* __restrict__ wrec_f,
                             unsigned short* __restrict__ wff,
                             unsigned short* __restrict__ wrec_sw) {
  int tid = blockIdx.x * 256 + threadIdx.x;
  if (tid < 409600) {
    int o = tid / 1600, k = tid % 1600;
    int kk = k >> 6, ci = k & 63;            // k = kk*64 + ci
    wff[tid] = f2bf(wff_f[o * 1600 + ci * 25 + kk]);
  } else if (tid < 409600 + 65536) {
    int i = tid - 409600;
    int o = i >> 8, ic = i & 255;
    wrec_sw[(((ic >> 3) << 8) + o) * 8 + (ic & 7)] = f2bf(wrec_f[i]);
  }
}

// ---------------------------------------------------------------------------
// x NCHW fp32 -> NHWC bf16: xt[(b*4096 + y*64 + x)*64 + ci].
__global__ __launch_bounds__(256) void transpose_x(
    const float* __restrict__ x, unsigned short* __restrict__ xt) {
  int g = blockIdx.x * 256 + threadIdx.x;          // 131072 = 32*4096
  const float* src = x + (long)(g >> 12) * CHW + (g & 4095);
  unsigned short* dst = xt + (long)g * 64;
#pragma unroll
  for (int oct = 0; oct < 8; ++oct) {
    alignas(16) unsigned short tmp[8];
#pragma unroll
    for (int d = 0; d < 8; ++d)
      tmp[d] = f2bf(src[(oct * 8 + d) * HW2]);
    *(int4*)(dst + oct * 8) = *(const int4*)tmp;
  }
}

// ---------------------------------------------------------------------------
// Conv as implicit GEMM, D[oc][n] (A = wff, B = x). Block 128oc x 128n,
// BK=32, grid (900, 2). Writes u0 fp16 [n][oc] as uint2 (4 oc per lane).
__global__ __launch_bounds__(256) void conv_kernel(
    const unsigned short* __restrict__ xt,
    const unsigned short* __restrict__ wff,
    unsigned short* __restrict__ u0_nc) {
  __shared__ short As[128 * 40];   // x-tile  [n][k]  pad 32->40
  __shared__ short Bs[128 * 40];   // wff     [oc][k]
  const int t = threadIdx.x;
  const int n0 = blockIdx.x * 128;
  const int oc0 = blockIdx.y * 128;
  const int lane = t & 63, w = t >> 6;
  const int q = lane >> 4, r = lane & 15;
  const int woc = w >> 1, wn = w & 1;      // oc-half, n-half
  const int qt = t & 3, mrow = t >> 2;     // staging: row mrow(+64), 16B qt

  int xbase[2];
#pragma unroll
  for (int p = 0; p < 2; ++p) {
    int n = n0 + p * 64 + mrow;
    int bb = n / 3600, rem = n - bb * 3600;
    int yy = rem / 60, xx = rem - yy * 60;
    xbase[p] = (bb * 4096 + yy * 64 + xx) * 64 + qt * 8;
  }

  f32x4 acc[4][4];
#pragma unroll
  for (int i = 0; i < 4; i++)
#pragma unroll
    for (int j = 0; j < 4; j++) acc[i][j] = (f32x4){0.f, 0.f, 0.f, 0.f};

  for (int c = 0; c < 50; ++c) {
    const int k0 = c * 32;
    const int kk = c >> 1;                 // ky*5+kx, uniform per chunk
    const int ky = kk / 5, kx = kk - ky * 5;
    const int choff = (ky * 64 + kx) * 64 + (c & 1) * 32;  // scalar-uniform

    __syncthreads();
#pragma unroll
    for (int p = 0; p < 2; ++p) {          // wff: 128 oc-rows x 32 k
      int m = p * 64 + mrow;
      *(int4*)(&Bs[m * 40 + qt * 8]) =
          *(const int4*)(wff + (oc0 + m) * 1600 + k0 + qt * 8);
    }
#pragma unroll
    for (int p = 0; p < 2; ++p) {          // x-tile: contiguous bf16 (NHWC)
      int m = p * 64 + mrow;
      *(int4*)(&As[m * 40 + qt * 8]) = *(const int4*)(xt + xbase[p] + choff);
    }
    __syncthreads();

    short8 xf[4], wf[4];
#pragma unroll
    for (int j = 0; j < 4; j++)
      xf[j] = *(const short8*)(&As[(wn * 64 + j * 16 + r) * 40 + q * 8]);
#pragma unroll
    for (int i = 0; i < 4; i++)
      wf[i] = *(const short8*)(&Bs[(woc * 64 + i * 16 + r) * 40 + q * 8]);
#pragma unroll
    for (int i = 0; i < 4; i++)
#pragma unroll
      for (int j = 0; j < 4; j++)
        acc[i][j] = __builtin_amdgcn_mfma_f32_16x16x32_bf16(wf[i], xf[j],
                                                            acc[i][j], 0, 0, 0);
  }

  // epilogue: lane holds 4 consecutive oc (d) at fixed n -> uint2 stores
#pragma unroll
  for (int j = 0; j < 4; j++) {
    const int n = n0 + wn * 64 + j * 16 + r;
#pragma unroll
    for (int i = 0; i < 4; i++) {
      const int oc = oc0 + woc * 64 + i * 16 + q * 4;
      alignas(8) unsigned short up[4];
#pragma unroll
      for (int d = 0; d < 4; ++d) up[d] = f2h(acc[i][j][d]);   // fp16 u0
      *(uint2*)(&u0_nc[n * 256 + oc]) = *(const uint2*)up;
    }
  }
}

// ---------------------------------------------------------------------------
// Shared GEMM: rec = W_rec @ a. Reads a (bf16) from a_lds, writes rec (fp16)
// back into a_lds in-place (row-major [n][oc]). Includes the two barriers.
__device__ __forceinline__ void gemm_rec(short* a_lds,
                                         const unsigned short* __restrict__
                                             wrec_sw,
                                         int w, int q, int r) {
  f32x4 acc[4][4];
#pragma unroll
  for (int i = 0; i < 4; i++)
#pragma unroll
    for (int j = 0; j < 4; j++) acc[i][j] = (f32x4){0.f, 0.f, 0.f, 0.f};

#pragma unroll
  for (int c = 0; c < 8; ++c) {
    short8 afr[4], bfr[4];
#pragma unroll
    for (int i = 0; i < 4; i++)
      afr[i] = *(const short8*)(wrec_sw +
               (((c * 4 + q) << 8) + w * 64 + i * 16 + r) * 8);
#pragma unroll
    for (int j = 0; j < 4; j++)
      bfr[j] = *(const short8*)(&a_lds[(j * 16 + r) * LDA + c * 32 + q * 8]);
#pragma unroll
    for (int i = 0; i < 4; i++)
#pragma unroll
      for (int j = 0; j < 4; j++)
        acc[i][j] = __builtin_amdgcn_mfma_f32_16x16x32_bf16(afr[i], bfr[j],
                                                            acc[i][j], 0, 0, 0);
  }
  __syncthreads();                         // all a_lds GEMM reads done
#pragma unroll
  for (int j = 0; j < 4; j++) {
    const int nr = j * 16 + r;
#pragma unroll
    for (int i = 0; i < 4; i++) {
      const int oc = w * 64 + i * 16 + q * 4;
      alignas(8) unsigned short rp[4];
#pragma unroll
      for (int d = 0; d < 4; ++d) rp[d] = f2h(acc[i][j][d]);
      *(uint2*)(&a_lds[nr * LDA + oc]) = *(const uint2*)rp;
    }
  }
  __syncthreads();
}

// ---------------------------------------------------------------------------
// Paired iteration: computes iterations itA (odd) and itA+1 per launch.
// Block = 64 n x 256 oc, grid 1800. u0 cached in 32 VGPRs across both steps;
// state u in 32 VGPRs between steps. Writes u_A -> uA, u_B -> uB; norms for
// both iterations. fp16 rounding chain identical to single-step path.
template <int FIRST>
__global__ __launch_bounds__(256, 2) void iter_pair(
    const unsigned short* __restrict__ wrec_sw,
    const unsigned short* __restrict__ u0, const float* __restrict__ thr,
    const unsigned short* __restrict__ uin,      // prev even state (uB)
    unsigned short* __restrict__ uA, unsigned short* __restrict__ uB,
    float* __restrict__ norms, int* __restrict__ flag, int itA) {
  __shared__ short a_lds[64 * LDA];
  __shared__ float red[16];

  const int t = threadIdx.x;
  if (!FIRST) {
    if (*(volatile int*)flag) return;            // converged earlier
    // first-crossing check over BOTH iterations of the previous launch
    float dA = norms[2 * (itA - 2)], nA = norms[2 * (itA - 2) + 1];
    float dB = norms[2 * (itA - 1)], nB = norms[2 * (itA - 1) + 1];
    if (dA < 1e-6f * nA || dB < 1e-6f * nB) {    // fro ratio < 1e-3
      if (t == 0) *flag = 1;
      return;
    }
  }

  const int n0 = blockIdx.x * 64;
  const int ch = t & 31;                   // 8-oc chunk
  const int row0 = t >> 5;                 // rows row0 + 8p
  const int occh = ch * 8;
  const int lane = t & 63, w = t >> 6;
  const int q = lane >> 4, r = lane & 15;

  float4 th0 = *(const float4*)(thr + occh);
  float4 th1 = *(const float4*)(thr + occh + 4);
  float thc[8] = {th0.x, th0.y, th0.z, th0.w, th1.x, th1.y, th1.z, th1.w};

  int4 sv[8];   // u state (fp16 packed): 32 VGPRs
  int4 u0c[8];  // u0 cached (fp16 packed): 32 VGPRs

  // ---- P1: load u + u0, a = relu(u - thr) -> LDS ----
#pragma unroll
  for (int p = 0; p < 8; ++p) {
    const int base = (n0 + row0 + p * 8) * 256 + occh;
    u0c[p] = *(const int4*)(u0 + base);
    if (FIRST)
      sv[p] = u0c[p];                      // a0 from u0; u_old = 0 handled below
    else
      sv[p] = *(const int4*)(uin + base);
    const unsigned short* hs = (const unsigned short*)&sv[p];
    alignas(16) unsigned short ap[8];
#pragma unroll
    for (int d = 0; d < 8; ++d) {
      float a = h2f(hs[d]) - thc[d];
      ap[d] = f2bf(a > 0.f ? a : 0.f);
    }
    *(int4*)(&a_lds[(row0 + p * 8) * LDA + occh]) = *(const int4*)ap;
  }
  __syncthreads();

  // ---- iteration A ----
  gemm_rec(a_lds, wrec_sw, w, q, r);

  float d2A = 0.f, n2A = 0.f;
#pragma unroll
  for (int p = 0; p < 8; ++p) {
    const int base = (n0 + row0 + p * 8) * 256 + occh;
    int4 rr = *(const int4*)(&a_lds[(row0 + p * 8) * LDA + occh]);
    const unsigned short* rs = (const unsigned short*)&rr;
    const unsigned short* us = (const unsigned short*)&u0c[p];
    const unsigned short* hs = (const unsigned short*)&sv[p];
    alignas(16) unsigned short up[8];
    alignas(16) unsigned short ap[8];
#pragma unroll
    for (int d = 0; d < 8; ++d) {
      float uo = FIRST ? 0.f : h2f(hs[d]);
      float un = 0.5f * uo + 0.5f * (h2f(us[d]) - h2f(rs[d]));
      float df = un - uo;
      d2A += df * df;
      n2A += un * un;
      up[d] = f2h(un);
      float ur = h2f(up[d]);               // rounded state (chain-exact)
      float a = ur - thc[d];
      ap[d] = f2bf(a > 0.f ? a : 0.f);
    }
    sv[p] = *(const int4*)up;
    *(int4*)(uA + base) = sv[p];           // odd-state write (for sel)
    *(int4*)(&a_lds[(row0 + p * 8) * LDA + occh]) = *(const int4*)ap;
  }
  __syncthreads();

  // ---- iteration B ----
  gemm_rec(a_lds, wrec_sw, w, q, r);

  float d2B = 0.f, n2B = 0.f;
#pragma unroll
  for (int p = 0; p < 8; ++p) {
    const int base = (n0 + row0 + p * 8) * 256 + occh;
    int4 rr = *(const int4*)(&a_lds[(row0 + p * 8) * LDA + occh]);
    const unsigned short* rs = (const unsigned short*)&rr;
    const unsigned short* us = (const unsigned short*)&u0c[p];
    const unsigned short* hs = (const unsigned short*)&sv[p];
    alignas(16) unsigned short up[8];
#pragma unroll
    for (int d = 0; d < 8; ++d) {
      float uo = h2f(hs[d]);
      float un = 0.5f * uo + 0.5f * (h2f(us[d]) - h2f(rs[d]));
      float df = un - uo;
      d2B += df * df;
      n2B += un * un;
      up[d] = f2h(un);
    }
    *(int4*)(uB + base) = *(const int4*)up;
  }

#pragma unroll
  for (int off = 32; off; off >>= 1) {
    d2A += __shfl_down(d2A, off, 64);
    n2A += __shfl_down(n2A, off, 64);
    d2B += __shfl_down(d2B, off, 64);
    n2B += __shfl_down(n2B, off, 64);
  }
  if (lane == 0) {
    red[w] = d2A; red[4 + w] = n2A; red[8 + w] = d2B; red[12 + w] = n2B;
  }
  __syncthreads();
  if (t == 0) {
    atomicAdd(&norms[2 * itA], red[0] + red[1] + red[2] + red[3]);
    atomicAdd(&norms[2 * itA + 1], red[4] + red[5] + red[6] + red[7]);
    atomicAdd(&norms[2 * itA + 2], red[8] + red[9] + red[10] + red[11]);
    atomicAdd(&norms[2 * itA + 3], red[12] + red[13] + red[14] + red[15]);
  }
}

// ---------------------------------------------------------------------------
// Single iteration it: uin -> uout. Used for it=41 (pair path, odd -> uA)
// and for the whole fallback chain (uB -> uB).
template <int FIRST>
__global__ __launch_bounds__(256, 3) void iter_one(
    const unsigned short* __restrict__ wrec_sw,
    const unsigned short* __restrict__ u0, const float* __restrict__ thr,
    const unsigned short* __restrict__ uin, unsigned short* __restrict__ uout,
    float* __restrict__ norms, int* __restrict__ flag, int it) {
  __shared__ short a_lds[64 * LDA];
  __shared__ float red[8];

  const int t = threadIdx.x;
  if (!FIRST) {
    if (*(volatile int*)flag) return;
    // check both predecessors (norms[0..1] are zero -> false for it=2)
    float dA = norms[2 * (it - 2)], nA = norms[2 * (it - 2) + 1];
    float dB = norms[2 * (it - 1)], nB = norms[2 * (it - 1) + 1];
    if (dA < 1e-6f * nA || dB < 1e-6f * nB) {
      if (t == 0) *flag = 1;
      return;
    }
  }

  const int n0 = blockIdx.x * 64;
  const int ch = t & 31;
  const int row0 = t >> 5;
  const int occh = ch * 8;
  const int lane = t & 63, w = t >> 6;
  const int q = lane >> 4, r = lane & 15;

  float4 th0 = *(const float4*)(thr + occh);
  float4 th1 = *(const float4*)(thr + occh + 4);
  float thc[8] = {th0.x, th0.y, th0.z, th0.w, th1.x, th1.y, th1.z, th1.w};

  int4 sv[8];
#pragma unroll
  for (int p = 0; p < 8; ++p) {
    const int base = (n0 + row0 + p * 8) * 256 + occh;
    if (FIRST)
      sv[p] = *(const int4*)(u0 + base);
    else
      sv[p] = *(const int4*)(uin + base);
    const unsigned short* hs = (const unsigned short*)&sv[p];
    alignas(16) unsigned short ap[8];
#pragma unroll
    for (int d = 0; d < 8; ++d) {
      float a = h2f(hs[d]) - thc[d];
      ap[d] = f2bf(a > 0.f ? a : 0.f);
    }
    *(int4*)(&a_lds[(row0 + p * 8) * LDA + occh]) = *(const int4*)ap;
  }
  __syncthreads();

  gemm_rec(a_lds, wrec_sw, w, q, r);

  float d2 = 0.f, n2 = 0.f;
#pragma unroll
  for (int p = 0; p < 8; ++p) {
    const int base = (n0 + row0 + p * 8) * 256 + occh;
    int4 rr = *(const int4*)(&a_lds[(row0 + p * 8) * LDA + occh]);
    const unsigned short* rs = (const unsigned short*)&rr;
    const unsigned short* hs = (const unsigned short*)&sv[p];
    float u0v[8];
    if (FIRST) {
#pragma unroll
      for (int d = 0; d < 8; ++d) u0v[d] = h2f(hs[d]);
    } else {
      int4 u0p = *(const int4*)(u0 + base);
      const unsigned short* us = (const unsigned short*)&u0p;
#pragma unroll
      for (int d = 0; d < 8; ++d) u0v[d] = h2f(us[d]);
    }
    alignas(16) unsigned short up[8];
#pragma unroll
    for (int d = 0; d < 8; ++d) {
      float uo = FIRST ? 0.f : h2f(hs[d]);
      float un = 0.5f * uo + 0.5f * (u0v[d] - h2f(rs[d]));
      float df = un - uo;
      d2 += df * df;
      n2 += un * un;
      up[d] = f2h(un);
    }
    *(int4*)(uout + base) = *(const int4*)up;
  }

#pragma unroll
  for (int off = 32; off; off >>= 1) {
    d2 += __shfl_down(d2, off, 64);
    n2 += __shfl_down(n2, off, 64);
  }
  if (lane == 0) { red[w] = d2; red[4 + w] = n2; }
  __syncthreads();
  if (t == 0) {
    atomicAdd(&norms[2 * it], red[0] + red[1] + red[2] + red[3]);
    atomicAdd(&norms[2 * it + 1], red[4] + red[5] + red[6] + red[7]);
  }
}

// ---------------------------------------------------------------------------
// sel: first it in [1,41] with d2 < 1e-6*n2 (else 41); odd -> uA (sel=0),
// even -> uB (sel=1).
__global__ void sel_kernel(const float* __restrict__ norms,
                           int* __restrict__ sel) {
  int it = 1;
  for (; it <= 41; ++it)
    if (norms[2 * it] < 1e-6f * norms[2 * it + 1]) break;
  if (it > 41) it = 41;
  *sel = (it & 1) ? 0 : 1;
}
__global__ void set_sel(int* __restrict__ sel, int v) { *sel = v; }

// ---------------------------------------------------------------------------
// Final: out(NCHW fp32) = relu(u - thr), u fp16 [n][oc], buffer chosen by sel.
__global__ __launch_bounds__(256) void final_out(
    const unsigned short* __restrict__ uA,
    const unsigned short* __restrict__ uB, const int* __restrict__ sel,
    const float* __restrict__ thr, float* __restrict__ out) {
  const unsigned short* u = (*sel) ? uB : uA;
  const int t = threadIdx.x, lane = t & 63, w = t >> 6;
  const int n = blockIdx.x * 64 + lane;
  const int b = n / 3600, s = n - b * 3600;
  float* ob = out + (long)b * 921600 + s;
  const unsigned short* ub = u + (long)n * 256 + w * 64;
#pragma unroll
  for (int g = 0; g < 8; ++g) {            // 8 groups x 8 fp16 = 64 oc
    int4 raw = *(const int4*)(ub + g * 8);
    const unsigned short* rs = (const unsigned short*)&raw;
#pragma unroll
    for (int d = 0; d < 8; ++d) {
      int oc = w * 64 + g * 8 + d;
      float v = h2f(rs[d]) - thr[oc];
      ob[oc * 3600] = v > 0.f ? v : 0.f;
    }
  }
}

// ---------------------------------------------------------------------------
extern "C" void kernel_launch(void* const* d_in, const int* in_sizes, int n_in,
                              void* d_out, int out_size, void* d_ws,
                              size_t ws_size, hipStream_t stream) {
  const float* x      = (const float*)d_in[0];
  const float* wff_f  = (const float*)d_in[1];
  const float* wrec_f = (const float*)d_in[2];
  const float* thr    = (const float*)d_in[3];
  float* out = (float*)d_out;

  char* ws = (char*)d_ws;
  int* flag = (int*)ws;                                      // [0,4)
  int* sel  = (int*)(ws + 8);                                // [8,12)
  float* norms = (float*)(ws + 64);                          // [64, 408)
  unsigned short* wff     = (unsigned short*)(ws + 1024);      // 819200 B
  unsigned short* wrec_sw = (unsigned short*)(ws + 851968);    // 131072 B
  // xt (16.8 MB) aliases the head of uB (59 MB): xt dies after conv; uB is
  // first written in iteration B of the first pair launch.
  unsigned short* xt = (unsigned short*)(ws + 983040);
  unsigned short* uB = (unsigned short*)(ws + 983040);         // 58982400 B
  unsigned short* u0 = (unsigned short*)(ws + 59965440);       // 58982400 B
  unsigned short* uA = (unsigned short*)(ws + 118947840);      // 58982400 B
  const size_t NEEDED = 118947840ULL + 58982400ULL;            // ~178 MB

  hipMemsetAsync(d_ws, 0, 1024, stream);  // flag + sel + norm slots
  cast_weights<<<1856, 256, 0, stream>>>(wff_f, wrec_f, wff, wrec_sw);
  transpose_x<<<512, 256, 0, stream>>>(x, xt);
  conv_kernel<<<dim3(900, 2), 256, 0, stream>>>(xt, wff, u0);

  if (ws_size >= NEEDED) {
    // paired path: (1,2), (3,4), ..., (39,40), then single 41 -> 41 bodies
    iter_pair<1><<<1800, 256, 0, stream>>>(wrec_sw, u0, thr, uB, uA, uB,
                                           norms, flag, 1);
    for (int itA = 3; itA <= 39; itA += 2)
      iter_pair<0><<<1800, 256, 0, stream>>>(wrec_sw, u0, thr, uB, uA, uB,
                                             norms, flag, itA);
    iter_one<0><<<1800, 256, 0, stream>>>(wrec_sw, u0, thr, uB, uA, norms,
                                          flag, 41);
    sel_kernel<<<1, 1, 0, stream>>>(norms, sel);
  } else {
    // fallback: proven single-step chain in uB
    iter_one<1><<<1800, 256, 0, stream>>>(wrec_sw, u0, thr, uB, uB, norms,
                                          flag, 1);
    for (int it = 2; it <= 41; ++it)
      iter_one<0><<<1800, 256, 0, stream>>>(wrec_sw, u0, thr, uB, uB, norms,
                                            flag, it);
    set_sel<<<1, 1, 0, stream>>>(sel, 1);
  }
  final_out<<<1800, 256, 0, stream>>>(uA, uB, sel, thr, out);
}

// Round 3
// 1211.712 us; speedup vs baseline: 2.9426x; 1.1707x over previous
//
#include <hip/hip_runtime.h>

// ---------------------------------------------------------------------------
// SparsePoolingLayer: u0 = conv5x5_valid(x, W_ff); iterate
//   u <- 0.5*u + 0.5*(u0 - W_rec @ a); a = relu(u - thr)
// until ||u_new - u||/||u_new|| < 1e-3 (device-checked), max 41 iterations.
//
// R11 design: occupancy-first pair kernel.
//  - R10 post-mortem: 226 us/pair at 18% occupancy -- 4-wave blocks with
//    acc(64 AGPR)+sv+u0c(64 VGPR) = ~192 unified regs -> 2 blocks/CU,
//    latency-serialized phases; +82 MB scratch spill (WRITE 200 vs 118 MB).
//  - R11: 512-thread / 8-wave iter blocks. Wave owns M=32 oc -> acc[2][4]
//    = 32 AGPRs; per-thread state sv[4]+u0c[4] = 32 VGPRs. launch_bounds
//    (512,4) targets <=128 unified -> 16 waves/CU (2 blocks), no spill.
//  - norm atomics spread over 8 slots (blockIdx&7): 8x less TCC contention.
//  - conv: LDS stride 40->42 shorts (21 banks, gcd(21,32)=1) to kill the
//    2.3e7 bank conflicts.
//  - Pair semantics unchanged: writes u_A (odd it) and u_B (even it);
//    sel_kernel picks first-crossing buffer. fp16 chain numerics identical.
// ---------------------------------------------------------------------------

typedef __attribute__((ext_vector_type(8))) short short8;
typedef __attribute__((ext_vector_type(4))) float f32x4;

#define NTOT 115200   // 32*60*60
#define CHW  262144   // 64*64*64
#define HW2  4096     // 64*64
#define LDA  264      // a_lds row stride in shorts (528 B)
#define LDC  42       // conv LDS row stride in shorts (84 B, 21 banks)

__device__ __forceinline__ unsigned short f2bf(float f) {
  unsigned int u = __float_as_uint(f);
  unsigned int r = u + 0x7FFFu + ((u >> 16) & 1u);
  return (unsigned short)(r >> 16);
}
__device__ __forceinline__ float bf2f(unsigned short h) {
  return __uint_as_float(((unsigned int)h) << 16);
}
__device__ __forceinline__ unsigned short f2h(float f) {
  _Float16 x = (_Float16)f;
  unsigned short r;
  __builtin_memcpy(&r, &x, 2);
  return r;
}
__device__ __forceinline__ float h2f(unsigned short h) {
  _Float16 x;
  __builtin_memcpy(&x, &h, 2);
  return (float)x;
}

// ---------------------------------------------------------------------------
// Weight prep:
//  wff[o][(ky*5+kx)*64+ci] bf16  (conv A operand rows)
//  wrec_sw: per-lane MFMA fragment order: for 8-wide ic-chunk cc (0..31),
//  oc row o: wrec_sw[((cc*256)+o)*8 + j] = W_rec[o][cc*8+j]
__global__ void cast_weights(const float* __restrict__ wff_f,
                             const float* __restrict__ wrec_f,
                             unsigned short* __restrict__ wff,
                             unsigned short* __restrict__ wrec_sw) {
  int tid = blockIdx.x * 256 + threadIdx.x;
  if (tid < 409600) {
    int o = tid / 1600, k = tid % 1600;
    int kk = k >> 6, ci = k & 63;            // k = kk*64 + ci
    wff[tid] = f2bf(wff_f[o * 1600 + ci * 25 + kk]);
  } else if (tid < 409600 + 65536) {
    int i = tid - 409600;
    int o = i >> 8, ic = i & 255;
    wrec_sw[(((ic >> 3) << 8) + o) * 8 + (ic & 7)] = f2bf(wrec_f[i]);
  }
}

// ---------------------------------------------------------------------------
// x NCHW fp32 -> NHWC bf16: xt[(b*4096 + y*64 + x)*64 + ci].
__global__ __launch_bounds__(256) void transpose_x(
    const float* __restrict__ x, unsigned short* __restrict__ xt) {
  int g = blockIdx.x * 256 + threadIdx.x;          // 131072 = 32*4096
  const float* src = x + (long)(g >> 12) * CHW + (g & 4095);
  unsigned short* dst = xt + (long)g * 64;
#pragma unroll
  for (int oct = 0; oct < 8; ++oct) {
    alignas(16) unsigned short tmp[8];
#pragma unroll
    for (int d = 0; d < 8; ++d)
      tmp[d] = f2bf(src[(oct * 8 + d) * HW2]);
    *(int4*)(dst + oct * 8) = *(const int4*)tmp;
  }
}

// ---------------------------------------------------------------------------
// Conv as implicit GEMM, D[oc][n] (A = wff, B = x). Block 128oc x 128n,
// BK=32, grid (900, 2). Writes u0 fp16 [n][oc] as uint2 (4 oc per lane).
__global__ __launch_bounds__(256) void conv_kernel(
    const unsigned short* __restrict__ xt,
    const unsigned short* __restrict__ wff,
    unsigned short* __restrict__ u0_nc) {
  __shared__ short As[128 * LDC];  // x-tile  [n][k]  pad 32->42
  __shared__ short Bs[128 * LDC];  // wff     [oc][k]
  const int t = threadIdx.x;
  const int n0 = blockIdx.x * 128;
  const int oc0 = blockIdx.y * 128;
  const int lane = t & 63, w = t >> 6;
  const int q = lane >> 4, r = lane & 15;
  const int woc = w >> 1, wn = w & 1;      // oc-half, n-half
  const int qt = t & 3, mrow = t >> 2;     // staging: row mrow(+64), 16B qt

  int xbase[2];
#pragma unroll
  for (int p = 0; p < 2; ++p) {
    int n = n0 + p * 64 + mrow;
    int bb = n / 3600, rem = n - bb * 3600;
    int yy = rem / 60, xx = rem - yy * 60;
    xbase[p] = (bb * 4096 + yy * 64 + xx) * 64 + qt * 8;
  }

  f32x4 acc[4][4];
#pragma unroll
  for (int i = 0; i < 4; i++)
#pragma unroll
    for (int j = 0; j < 4; j++) acc[i][j] = (f32x4){0.f, 0.f, 0.f, 0.f};

  for (int c = 0; c < 50; ++c) {
    const int k0 = c * 32;
    const int kk = c >> 1;                 // ky*5+kx, uniform per chunk
    const int ky = kk / 5, kx = kk - ky * 5;
    const int choff = (ky * 64 + kx) * 64 + (c & 1) * 32;  // scalar-uniform

    __syncthreads();
#pragma unroll
    for (int p = 0; p < 2; ++p) {          // wff: 128 oc-rows x 32 k
      int m = p * 64 + mrow;
      *(int4*)(&Bs[m * LDC + qt * 8]) =
          *(const int4*)(wff + (oc0 + m) * 1600 + k0 + qt * 8);
    }
#pragma unroll
    for (int p = 0; p < 2; ++p) {          // x-tile: contiguous bf16 (NHWC)
      int m = p * 64 + mrow;
      *(int4*)(&As[m * LDC + qt * 8]) = *(const int4*)(xt + xbase[p] + choff);
    }
    __syncthreads();

    short8 xf[4], wf[4];
#pragma unroll
    for (int j = 0; j < 4; j++)
      xf[j] = *(const short8*)(&As[(wn * 64 + j * 16 + r) * LDC + q * 8]);
#pragma unroll
    for (int i = 0; i < 4; i++)
      wf[i] = *(const short8*)(&Bs[(woc * 64 + i * 16 + r) * LDC + q * 8]);
#pragma unroll
    for (int i = 0; i < 4; i++)
#pragma unroll
      for (int j = 0; j < 4; j++)
        acc[i][j] = __builtin_amdgcn_mfma_f32_16x16x32_bf16(wf[i], xf[j],
                                                            acc[i][j], 0, 0, 0);
  }

  // epilogue: lane holds 4 consecutive oc (d) at fixed n -> uint2 stores
#pragma unroll
  for (int j = 0; j < 4; j++) {
    const int n = n0 + wn * 64 + j * 16 + r;
#pragma unroll
    for (int i = 0; i < 4; i++) {
      const int oc = oc0 + woc * 64 + i * 16 + q * 4;
      alignas(8) unsigned short up[4];
#pragma unroll
      for (int d = 0; d < 4; ++d) up[d] = f2h(acc[i][j][d]);   // fp16 u0
      *(uint2*)(&u0_nc[n * 256 + oc]) = *(const uint2*)up;
    }
  }
}

// ---------------------------------------------------------------------------
// 8-wave GEMM: rec = W_rec @ a. Wave w owns oc rows [32w, 32w+32). Reads a
// (bf16) from a_lds, writes rec (fp16) back in-place. Includes barriers.
__device__ __forceinline__ void gemm_rec8(short* a_lds,
                                          const unsigned short* __restrict__
                                              wrec_sw,
                                          int w, int q, int r) {
  f32x4 acc[2][4];
#pragma unroll
  for (int i = 0; i < 2; i++)
#pragma unroll
    for (int j = 0; j < 4; j++) acc[i][j] = (f32x4){0.f, 0.f, 0.f, 0.f};

#pragma unroll
  for (int c = 0; c < 8; ++c) {
    short8 afr[2], bfr[4];
#pragma unroll
    for (int i = 0; i < 2; i++)
      afr[i] = *(const short8*)(wrec_sw +
               (((c * 4 + q) << 8) + w * 32 + i * 16 + r) * 8);
#pragma unroll
    for (int j = 0; j < 4; j++)
      bfr[j] = *(const short8*)(&a_lds[(j * 16 + r) * LDA + c * 32 + q * 8]);
#pragma unroll
    for (int i = 0; i < 2; i++)
#pragma unroll
      for (int j = 0; j < 4; j++)
        acc[i][j] = __builtin_amdgcn_mfma_f32_16x16x32_bf16(afr[i], bfr[j],
                                                            acc[i][j], 0, 0, 0);
  }
  __syncthreads();                         // all a_lds GEMM reads done
#pragma unroll
  for (int j = 0; j < 4; j++) {
    const int nr = j * 16 + r;
#pragma unroll
    for (int i = 0; i < 2; i++) {
      const int oc = w * 32 + i * 16 + q * 4;
      alignas(8) unsigned short rp[4];
#pragma unroll
      for (int d = 0; d < 4; ++d) rp[d] = f2h(acc[i][j][d]);
      *(uint2*)(&a_lds[nr * LDA + oc]) = *(const uint2*)rp;
    }
  }
  __syncthreads();
}

// ---------------------------------------------------------------------------
// Paired iteration, 512 threads / 8 waves, grid 1800 (64 n each).
// u0 cached in 16 VGPRs; state u in 16 VGPRs between steps. Writes u_A -> uA,
// u_B -> uB; norm partials to slot blockIdx&7.
template <int FIRST>
__global__ __launch_bounds__(512, 4) void iter_pair(
    const unsigned short* __restrict__ wrec_sw,
    const unsigned short* __restrict__ u0, const float* __restrict__ thr,
    const unsigned short* __restrict__ uin,      // prev even state (uB)
    unsigned short* __restrict__ uA, unsigned short* __restrict__ uB,
    float* __restrict__ norms, int* __restrict__ flag, int itA) {
  __shared__ short a_lds[64 * LDA];
  __shared__ float red[32];

  const int t = threadIdx.x;
  if (!FIRST) {
    if (*(volatile int*)flag) return;            // converged earlier
    float dA = 0.f, nA = 0.f, dB = 0.f, nB = 0.f;
#pragma unroll
    for (int s = 0; s < 8; ++s) {
      dA += norms[(itA - 2) * 16 + s];
      nA += norms[(itA - 2) * 16 + 8 + s];
      dB += norms[(itA - 1) * 16 + s];
      nB += norms[(itA - 1) * 16 + 8 + s];
    }
    if (dA < 1e-6f * nA || dB < 1e-6f * nB) {    // fro ratio < 1e-3
      if (t == 0) *flag = 1;
      return;
    }
  }

  const int n0 = blockIdx.x * 64;
  const int ch = t & 31;                   // 8-oc chunk
  const int row0 = t >> 5;                 // rows row0 + 16p (row0 in 0..15)
  const int occh = ch * 8;
  const int lane = t & 63, w = t >> 6;     // w in 0..7
  const int q = lane >> 4, r = lane & 15;

  float4 th0 = *(const float4*)(thr + occh);
  float4 th1 = *(const float4*)(thr + occh + 4);
  float thc[8] = {th0.x, th0.y, th0.z, th0.w, th1.x, th1.y, th1.z, th1.w};

  int4 sv[4];   // u state (fp16 packed): 16 VGPRs
  int4 u0c[4];  // u0 cached (fp16 packed): 16 VGPRs

  // ---- P1: load u + u0, a = relu(u - thr) -> LDS ----
#pragma unroll
  for (int p = 0; p < 4; ++p) {
    const int base = (n0 + row0 + p * 16) * 256 + occh;
    u0c[p] = *(const int4*)(u0 + base);
    if (FIRST)
      sv[p] = u0c[p];                      // a0 from u0; u_old = 0 below
    else
      sv[p] = *(const int4*)(uin + base);
    const unsigned short* hs = (const unsigned short*)&sv[p];
    alignas(16) unsigned short ap[8];
#pragma unroll
    for (int d = 0; d < 8; ++d) {
      float a = h2f(hs[d]) - thc[d];
      ap[d] = f2bf(a > 0.f ? a : 0.f);
    }
    *(int4*)(&a_lds[(row0 + p * 16) * LDA + occh]) = *(const int4*)ap;
  }
  __syncthreads();

  // ---- iteration A ----
  gemm_rec8(a_lds, wrec_sw, w, q, r);

  float d2A = 0.f, n2A = 0.f;
#pragma unroll
  for (int p = 0; p < 4; ++p) {
    const int base = (n0 + row0 + p * 16) * 256 + occh;
    int4 rr = *(const int4*)(&a_lds[(row0 + p * 16) * LDA + occh]);
    const unsigned short* rs = (const unsigned short*)&rr;
    const unsigned short* us = (const unsigned short*)&u0c[p];
    const unsigned short* hs = (const unsigned short*)&sv[p];
    alignas(16) unsigned short up[8];
    alignas(16) unsigned short ap[8];
#pragma unroll
    for (int d = 0; d < 8; ++d) {
      float uo = FIRST ? 0.f : h2f(hs[d]);
      float un = 0.5f * uo + 0.5f * (h2f(us[d]) - h2f(rs[d]));
      float df = un - uo;
      d2A += df * df;
      n2A += un * un;
      up[d] = f2h(un);
      float ur = h2f(up[d]);               // rounded state (chain-exact)
      float a = ur - thc[d];
      ap[d] = f2bf(a > 0.f ? a : 0.f);
    }
    sv[p] = *(const int4*)up;
    *(int4*)(uA + base) = sv[p];           // odd-state write (for sel)
    *(int4*)(&a_lds[(row0 + p * 16) * LDA + occh]) = *(const int4*)ap;
  }
  __syncthreads();

  // ---- iteration B ----
  gemm_rec8(a_lds, wrec_sw, w, q, r);

  float d2B = 0.f, n2B = 0.f;
#pragma unroll
  for (int p = 0; p < 4; ++p) {
    const int base = (n0 + row0 + p * 16) * 256 + occh;
    int4 rr = *(const int4*)(&a_lds[(row0 + p * 16) * LDA + occh]);
    const unsigned short* rs = (const unsigned short*)&rr;
    const unsigned short* us = (const unsigned short*)&u0c[p];
    const unsigned short* hs = (const unsigned short*)&sv[p];
    alignas(16) unsigned short up[8];
#pragma unroll
    for (int d = 0; d < 8; ++d) {
      float uo = h2f(hs[d]);
      float un = 0.5f * uo + 0.5f * (h2f(us[d]) - h2f(rs[d]));
      float df = un - uo;
      d2B += df * df;
      n2B += un * un;
      up[d] = f2h(un);
    }
    *(int4*)(uB + base) = *(const int4*)up;
  }

  // ---- reduction: wave -> block -> 8-slot atomics ----
#pragma unroll
  for (int off = 32; off; off >>= 1) {
    d2A += __shfl_down(d2A, off, 64);
    n2A += __shfl_down(n2A, off, 64);
    d2B += __shfl_down(d2B, off, 64);
    n2B += __shfl_down(n2B, off, 64);
  }
  if (lane == 0) {
    red[w] = d2A; red[8 + w] = n2A; red[16 + w] = d2B; red[24 + w] = n2B;
  }
  __syncthreads();
  if (t == 0) {
    float a0 = 0.f, a1 = 0.f, a2 = 0.f, a3 = 0.f;
#pragma unroll
    for (int s = 0; s < 8; ++s) {
      a0 += red[s]; a1 += red[8 + s]; a2 += red[16 + s]; a3 += red[24 + s];
    }
    const int slot = blockIdx.x & 7;
    atomicAdd(&norms[itA * 16 + slot], a0);
    atomicAdd(&norms[itA * 16 + 8 + slot], a1);
    atomicAdd(&norms[(itA + 1) * 16 + slot], a2);
    atomicAdd(&norms[(itA + 1) * 16 + 8 + slot], a3);
  }
}

// ---------------------------------------------------------------------------
// Single iteration it: uin -> uout (512 threads / 8 waves). Used for it=41
// (pair path, odd -> uA) and for the whole fallback chain (uB -> uB).
template <int FIRST>
__global__ __launch_bounds__(512, 4) void iter_one(
    const unsigned short* __restrict__ wrec_sw,
    const unsigned short* __restrict__ u0, const float* __restrict__ thr,
    const unsigned short* __restrict__ uin, unsigned short* __restrict__ uout,
    float* __restrict__ norms, int* __restrict__ flag, int it) {
  __shared__ short a_lds[64 * LDA];
  __shared__ float red[16];

  const int t = threadIdx.x;
  if (!FIRST) {
    if (*(volatile int*)flag) return;
    float dA = 0.f, nA = 0.f, dB = 0.f, nB = 0.f;
#pragma unroll
    for (int s = 0; s < 8; ++s) {
      dA += norms[(it - 2) * 16 + s];
      nA += norms[(it - 2) * 16 + 8 + s];
      dB += norms[(it - 1) * 16 + s];
      nB += norms[(it - 1) * 16 + 8 + s];
    }
    if (dA < 1e-6f * nA || dB < 1e-6f * nB) {
      if (t == 0) *flag = 1;
      return;
    }
  }

  const int n0 = blockIdx.x * 64;
  const int ch = t & 31;
  const int row0 = t >> 5;
  const int occh = ch * 8;
  const int lane = t & 63, w = t >> 6;
  const int q = lane >> 4, r = lane & 15;

  float4 th0 = *(const float4*)(thr + occh);
  float4 th1 = *(const float4*)(thr + occh + 4);
  float thc[8] = {th0.x, th0.y, th0.z, th0.w, th1.x, th1.y, th1.z, th1.w};

  int4 sv[4];
  int4 u0c[4];
#pragma unroll
  for (int p = 0; p < 4; ++p) {
    const int base = (n0 + row0 + p * 16) * 256 + occh;
    u0c[p] = *(const int4*)(u0 + base);
    if (FIRST)
      sv[p] = u0c[p];
    else
      sv[p] = *(const int4*)(uin + base);
    const unsigned short* hs = (const unsigned short*)&sv[p];
    alignas(16) unsigned short ap[8];
#pragma unroll
    for (int d = 0; d < 8; ++d) {
      float a = h2f(hs[d]) - thc[d];
      ap[d] = f2bf(a > 0.f ? a : 0.f);
    }
    *(int4*)(&a_lds[(row0 + p * 16) * LDA + occh]) = *(const int4*)ap;
  }
  __syncthreads();

  gemm_rec8(a_lds, wrec_sw, w, q, r);

  float d2 = 0.f, n2 = 0.f;
#pragma unroll
  for (int p = 0; p < 4; ++p) {
    const int base = (n0 + row0 + p * 16) * 256 + occh;
    int4 rr = *(const int4*)(&a_lds[(row0 + p * 16) * LDA + occh]);
    const unsigned short* rs = (const unsigned short*)&rr;
    const unsigned short* us = (const unsigned short*)&u0c[p];
    const unsigned short* hs = (const unsigned short*)&sv[p];
    alignas(16) unsigned short up[8];
#pragma unroll
    for (int d = 0; d < 8; ++d) {
      float uo = FIRST ? 0.f : h2f(hs[d]);
      float un = 0.5f * uo + 0.5f * (h2f(us[d]) - h2f(rs[d]));
      float df = un - uo;
      d2 += df * df;
      n2 += un * un;
      up[d] = f2h(un);
    }
    *(int4*)(uout + base) = *(const int4*)up;
  }

#pragma unroll
  for (int off = 32; off; off >>= 1) {
    d2 += __shfl_down(d2, off, 64);
    n2 += __shfl_down(n2, off, 64);
  }
  if (lane == 0) { red[w] = d2; red[8 + w] = n2; }
  __syncthreads();
  if (t == 0) {
    float a0 = 0.f, a1 = 0.f;
#pragma unroll
    for (int s = 0; s < 8; ++s) { a0 += red[s]; a1 += red[8 + s]; }
    const int slot = blockIdx.x & 7;
    atomicAdd(&norms[it * 16 + slot], a0);
    atomicAdd(&norms[it * 16 + 8 + slot], a1);
  }
}

// ---------------------------------------------------------------------------
// sel: first it in [1,41] with d2 < 1e-6*n2 (else 41); odd -> uA (sel=0),
// even -> uB (sel=1).
__global__ void sel_kernel(const float* __restrict__ norms,
                           int* __restrict__ sel) {
  int it = 1;
  for (; it <= 41; ++it) {
    float d = 0.f, n = 0.f;
    for (int s = 0; s < 8; ++s) {
      d += norms[it * 16 + s];
      n += norms[it * 16 + 8 + s];
    }
    if (d < 1e-6f * n) break;
  }
  if (it > 41) it = 41;
  *sel = (it & 1) ? 0 : 1;
}
__global__ void set_sel(int* __restrict__ sel, int v) { *sel = v; }

// ---------------------------------------------------------------------------
// Final: out(NCHW fp32) = relu(u - thr), u fp16 [n][oc], buffer chosen by sel.
__global__ __launch_bounds__(256) void final_out(
    const unsigned short* __restrict__ uA,
    const unsigned short* __restrict__ uB, const int* __restrict__ sel,
    const float* __restrict__ thr, float* __restrict__ out) {
  const unsigned short* u = (*sel) ? uB : uA;
  const int t = threadIdx.x, lane = t & 63, w = t >> 6;
  const int n = blockIdx.x * 64 + lane;
  const int b = n / 3600, s = n - b * 3600;
  float* ob = out + (long)b * 921600 + s;
  const unsigned short* ub = u + (long)n * 256 + w * 64;
#pragma unroll
  for (int g = 0; g < 8; ++g) {            // 8 groups x 8 fp16 = 64 oc
    int4 raw = *(const int4*)(ub + g * 8);
    const unsigned short* rs = (const unsigned short*)&raw;
#pragma unroll
    for (int d = 0; d < 8; ++d) {
      int oc = w * 64 + g * 8 + d;
      float v = h2f(rs[d]) - thr[oc];
      ob[oc * 3600] = v > 0.f ? v : 0.f;
    }
  }
}

// ---------------------------------------------------------------------------
extern "C" void kernel_launch(void* const* d_in, const int* in_sizes, int n_in,
                              void* d_out, int out_size, void* d_ws,
                              size_t ws_size, hipStream_t stream) {
  const float* x      = (const float*)d_in[0];
  const float* wff_f  = (const float*)d_in[1];
  const float* wrec_f = (const float*)d_in[2];
  const float* thr    = (const float*)d_in[3];
  float* out = (float*)d_out;

  char* ws = (char*)d_ws;
  int* flag = (int*)ws;                                      // [0,4)
  int* sel  = (int*)(ws + 8);                                // [8,12)
  float* norms = (float*)(ws + 64);                          // 42*16*4 = 2688 B
  unsigned short* wff     = (unsigned short*)(ws + 4096);      // 819200 B
  unsigned short* wrec_sw = (unsigned short*)(ws + 823296);    // 131072 B
  // xt (16.8 MB) aliases the head of uB (59 MB): xt dies after conv; uB is
  // first written in iteration B of the first pair launch.
  unsigned short* xt = (unsigned short*)(ws + 983040);
  unsigned short* uB = (unsigned short*)(ws + 983040);         // 58982400 B
  unsigned short* u0 = (unsigned short*)(ws + 59965440);       // 58982400 B
  unsigned short* uA = (unsigned short*)(ws + 118947840);      // 58982400 B
  const size_t NEEDED = 118947840ULL + 58982400ULL;            // ~178 MB

  hipMemsetAsync(d_ws, 0, 4096, stream);  // flag + sel + norm slots
  cast_weights<<<1856, 256, 0, stream>>>(wff_f, wrec_f, wff, wrec_sw);
  transpose_x<<<512, 256, 0, stream>>>(x, xt);
  conv_kernel<<<dim3(900, 2), 256, 0, stream>>>(xt, wff, u0);

  if (ws_size >= NEEDED) {
    // paired path: (1,2), (3,4), ..., (39,40), then single 41 -> 41 bodies
    iter_pair<1><<<1800, 512, 0, stream>>>(wrec_sw, u0, thr, uB, uA, uB,
                                           norms, flag, 1);
    for (int itA = 3; itA <= 39; itA += 2)
      iter_pair<0><<<1800, 512, 0, stream>>>(wrec_sw, u0, thr, uB, uA, uB,
                                             norms, flag, itA);
    iter_one<0><<<1800, 512, 0, stream>>>(wrec_sw, u0, thr, uB, uA, norms,
                                          flag, 41);
    sel_kernel<<<1, 1, 0, stream>>>(norms, sel);
  } else {
    // fallback: proven single-step chain in uB
    iter_one<1><<<1800, 512, 0, stream>>>(wrec_sw, u0, thr, uB, uB, norms,
                                          flag, 1);
    for (int it = 2; it <= 41; ++it)
      iter_one<0><<<1800, 512, 0, stream>>>(wrec_sw, u0, thr, uB, uB, norms,
                                            flag, it);
    set_sel<<<1, 1, 0, stream>>>(sel, 1);
  }
  final_out<<<1800, 256, 0, stream>>>(uA, uB, sel, thr, out);
}